// Round 20
// baseline (506.081 us; speedup 1.0000x reference)
//
#include <hip/hip_runtime.h>
#include <hip/hip_bf16.h>

typedef __attribute__((ext_vector_type(8))) short bf16x8v;
typedef __attribute__((ext_vector_type(4))) float f32x4v;

#define DEV __device__ __forceinline__

constexpr int Bn = 8, Sn = 4096, En = 512, Hn = 512;
constexpr int Mn = Bn * Sn;          // 32768 rows
constexpr int NCc = 128, CHc = 32;   // scan: 128 chunks of 32
constexpr size_t SLOT = 33579008;    // = 8*4099*512*2 bytes (padded-conv buffer), 4096-aligned

// ---------- math helpers ----------
DEV float bfu(unsigned u){ union{unsigned v; float f;} c; c.v = u << 16; return c.f; }

DEV void gload16(const void* g, void* l){
  __builtin_amdgcn_global_load_lds((const __attribute__((address_space(1))) void*)g,
                                   (__attribute__((address_space(3))) void*)l, 16, 0, 0);
}

// linear-space gates: f' = (1+e^-i)/(2+e^-f+e^-i), i' = (1+e^-f)/(...), g = x>=0? x+.5 : sigmoid(x)
DEV void gate_lin(float f, float i, float hp, float& fp, float& ig){
  const float ef = __expf(-f);
  const float ei = __expf(-i);
  const float rd = 1.f / (2.f + ef + ei);
  fp = (1.f + ei) * rd;
  const float ipv = (1.f + ef) * rd;
  const float g = (hp >= 0.f) ? (hp + 0.5f) : (1.f / (1.f + __expf(-hp)));
  ig = ipv * g;
}

DEV float g_of(float x){ return (x >= 0.f) ? (x + 0.5f) : (1.f / (1.f + __expf(-x))); }

// ---------- bf16 MFMA GEMM, 256x128 tile, BK=32, 8 waves (4Mx2N), 512 thr ----------
// BEST-KNOWN (r17): 2 blocks/CU (3-buffer 72KB LDS, (512,4) -> 56 VGPR no
// spill), coalesced staging (4 lanes per 64B row-line) with involutive
// chunk-XOR cs=cp^((row>>1)&3) on both global source and ds_read address,
// ONE barrier per K-tile:
//   [read bfv+af01 || stageA(t+2)] -> 8 MFMA (no barrier)
//   [read af23     || stageB(t+2)] -> vmcnt(3|0)+lgkmcnt(0) -> s_barrier -> 8 MFMA
// Hazards: RAW — tile t+1's 3 stages are the oldest outstanding at the tile-t
// wait; vmcnt(3) drains them, barrier makes it global. WAR — buf cur is
// restaged at t+1 after the tile-t barrier; own reads retired via MFMA lgkm +
// the explicit lgkmcnt(0). Ladder: r4 164us -> r7 117 -> r14 94 -> r17 87us
// per big GEMM (~780 TF, ~85-90% of the plain-HIP simple-schedule ceiling).
// C[M,N] = A(row-mapped)[M,K] * Bw[N,K]^T + bias
// RES: 0 none, 1 add bf16 residual at res[r*rRS + (r>>12)*rBP + rOff + c]
template<int RES, bool RELU, bool OUTF32>
__global__ __launch_bounds__(512, 4)
void gemm_bf16(const __hip_bfloat16* __restrict__ A,
               const __hip_bfloat16* __restrict__ Bw,
               int N, int K, int aRS, int aBP,
               const float* __restrict__ bias,
               const __hip_bfloat16* __restrict__ res, int rRS, int rBP, int rOff,
               void* __restrict__ out)
{
  __shared__ __align__(16) __hip_bfloat16 Al[3][256][32];   // 48 KB
  __shared__ __align__(16) __hip_bfloat16 Bl[3][128][32];   // 24 KB
  const int tid  = threadIdx.x;
  const int lane = tid & 63;
  const int w    = tid >> 6;            // 0..7
  const int ntn  = N >> 7;
  // T1: XCD-aware bijective swizzle (all grids are multiples of 8)
  const int nwg = gridDim.x;
  int wg = blockIdx.x;
  if ((nwg & 7) == 0) wg = ((wg & 7) * (nwg >> 3)) + (wg >> 3);
  const int bm = wg / ntn, bn = wg % ntn;
  const int rowBase = bm << 8, colBase = bn << 7;
  const int wm = w >> 1, wn = w & 1;    // 4 x 2 wave grid; wave tile 64x64
  const int r0 = lane & 15, kc = lane >> 4;
  const int rc = (kc ^ ((r0 >> 1) & 3)) << 3;   // XOR'd chunk offset within [32k] row

  f32x4v acc[4][4];
  #pragma unroll
  for (int i=0;i<4;i++)
    #pragma unroll
    for (int j=0;j<4;j++)
      #pragma unroll
      for (int q=0;q<4;q++) acc[i][j][q] = 0.f;

  // coalesced staging slots: slot s -> row=s>>2, cp=s&3; src chunk cs=cp^((row>>1)&3)
  const int ar0 = tid >> 2, acp = tid & 3;
  const int ar1 = 128 + ar0;
  const int acs0 = acp ^ ((ar0 >> 1) & 3);
  const int acs1 = acp ^ ((ar1 >> 1) & 3);
  const int rg0 = rowBase + ar0, rg1 = rowBase + ar1;
  const size_t aoff0 = (size_t)rg0*aRS + (size_t)(rg0>>12)*aBP + (acs0<<3);
  const size_t aoff1 = (size_t)rg1*aRS + (size_t)(rg1>>12)*aBP + (acs1<<3);
  const size_t boff  = (size_t)(colBase + ar0)*K + (acs0<<3);

  auto stageA = [&](int buf, int t){
    const int ke = t << 5;
    gload16(A + aoff0 + ke, &Al[buf][ar0][acp<<3]);
    gload16(A + aoff1 + ke, &Al[buf][ar1][acp<<3]);
  };
  auto stageB = [&](int buf, int t){
    gload16(Bw + boff + (t<<5), &Bl[buf][ar0][acp<<3]);
  };

  const int NT = K >> 5;                // 16 (K=512) or 64 (K=2048)

  // prologue: stage tiles 0 and 1; tile 0 must land (tile 1's 3 stay in flight)
  stageA(0,0); stageB(0,0); stageA(1,1); stageB(1,1);
  asm volatile("s_waitcnt vmcnt(3)" ::: "memory");
  __builtin_amdgcn_s_barrier();

  int cur = 0;
  for (int t=0; t<NT; t++){
    int nb = cur + 2; if (nb >= 3) nb -= 3;
    const bool pre = (t+2 < NT);
    bf16x8v bfv[4], af[2];
    // ---- p0: frags + stageA, then 8 MFMA (no barrier) ----
    #pragma unroll
    for (int ni=0;ni<4;ni++) bfv[ni] = *(const bf16x8v*)&Bl[cur][(wn<<6)+(ni<<4)+r0][rc];
    af[0] = *(const bf16x8v*)&Al[cur][(wm<<6)+r0][rc];
    af[1] = *(const bf16x8v*)&Al[cur][(wm<<6)+16+r0][rc];
    if (pre) stageA(nb, t+2);
    __builtin_amdgcn_s_setprio(1);
    #pragma unroll
    for (int m=0;m<2;m++)
      #pragma unroll
      for (int ni=0;ni<4;ni++)
        acc[m][ni] = __builtin_amdgcn_mfma_f32_16x16x32_bf16(af[m], bfv[ni], acc[m][ni], 0, 0, 0);
    __builtin_amdgcn_s_setprio(0);
    // ---- p1: frags + stageB, single combined wait + barrier, 8 MFMA ----
    af[0] = *(const bf16x8v*)&Al[cur][(wm<<6)+32+r0][rc];
    af[1] = *(const bf16x8v*)&Al[cur][(wm<<6)+48+r0][rc];
    if (pre) stageB(nb, t+2);
    if (pre) asm volatile("s_waitcnt vmcnt(3) lgkmcnt(0)" ::: "memory");
    else     asm volatile("s_waitcnt vmcnt(0) lgkmcnt(0)" ::: "memory");
    __builtin_amdgcn_s_barrier();
    __builtin_amdgcn_s_setprio(1);
    #pragma unroll
    for (int m=0;m<2;m++)
      #pragma unroll
      for (int ni=0;ni<4;ni++)
        acc[2+m][ni] = __builtin_amdgcn_mfma_f32_16x16x32_bf16(af[m], bfv[ni], acc[2+m][ni], 0, 0, 0);
    __builtin_amdgcn_s_setprio(0);
    cur = (cur + 1 == 3) ? 0 : cur + 1;
  }

  float* outF = (float*)out;
  __hip_bfloat16* outH = (__hip_bfloat16*)out;
  const int q = lane >> 4;
  float bia[4];
  #pragma unroll
  for (int ni=0;ni<4;ni++) bia[ni] = bias[colBase + (wn<<6) + (ni<<4) + r0];
  #pragma unroll
  for (int mi=0;mi<4;mi++){
    const int rb = rowBase + (wm<<6) + (mi<<4) + (q<<2);
    #pragma unroll
    for (int j=0;j<4;j++){
      const int r = rb + j;
      #pragma unroll
      for (int ni=0;ni<4;ni++){        // ni innermost: adjacent 32B chunks per row
        const int c = colBase + (wn<<6) + (ni<<4) + r0;
        float v = acc[mi][ni][j] + bia[ni];
        if constexpr (RES==1) v += __bfloat162float(res[(size_t)r*rRS + (size_t)(r>>12)*rBP + rOff + c]);
        if constexpr (RELU)   v = fmaxf(v, 0.f);
        if constexpr (OUTF32) outF[(size_t)r*N + c] = v;
        else                  outH[(size_t)r*N + c] = __float2bfloat16(v);
      }
    }
  }
}

// ---------- LayerNorm over last dim (512), one block per row, bf16 out ----------
template<bool INF32>
__global__ __launch_bounds__(256)
void ln_k(const void* __restrict__ xin, const float* __restrict__ g, const float* __restrict__ bta,
          __hip_bfloat16* __restrict__ outB, int bBP, int bOff)
{
  const int row = blockIdx.x, tid = threadIdx.x;
  float x0, x1;
  if constexpr (INF32){
    const float2 xv = ((const float2*)((const float*)xin + (size_t)row*En))[tid];
    x0 = xv.x; x1 = xv.y;
  } else {
    const unsigned u = ((const unsigned*)((const __hip_bfloat16*)xin + (size_t)row*En))[tid];
    x0 = bfu(u & 0xffffu); x1 = bfu(u >> 16);
  }
  float s = x0 + x1, sq = x0*x0 + x1*x1;
  #pragma unroll
  for (int off=32; off; off>>=1){ s += __shfl_down(s, off); sq += __shfl_down(sq, off); }
  __shared__ float red[8];
  const int w = tid >> 6, lane = tid & 63;
  if (lane == 0){ red[w] = s; red[4+w] = sq; }
  __syncthreads();
  s  = red[0]+red[1]+red[2]+red[3];
  sq = red[4]+red[5]+red[6]+red[7];
  const float mu   = s * (1.f/En);
  const float rstd = rsqrtf(sq * (1.f/En) - mu*mu + 1e-5f);
  const float2 gv = ((const float2*)g)[tid];
  const float2 bv = ((const float2*)bta)[tid];
  const float y0 = (x0 - mu)*rstd*gv.x + bv.x;
  const float y1 = (x1 - mu)*rstd*gv.y + bv.y;
  const size_t base = (size_t)row*En + (size_t)(row>>12)*bBP + bOff + tid*2;
  __hip_bfloat162 o; o.x = __float2bfloat16(y0); o.y = __float2bfloat16(y1);
  *(__hip_bfloat162*)(outB + base) = o;
}

// ---------- linear-space chunked scan over gates packed [row][1536] = f | i | h~ ----------
__global__ __launch_bounds__(256)
void scan_phaseA(const __hip_bfloat16* __restrict__ gi,
                 float* __restrict__ Aagg, float* __restrict__ Bagg)
{
  const int gid = blockIdx.x*256 + threadIdx.x;        // (b, c, hp)  hp in [0,256)
  const int hp = gid & 255, c = (gid >> 8) & 127, b = gid >> 15;
  size_t base = ((size_t)b*Sn + (size_t)c*CHc)*1536 + 2*hp;
  float A0 = 1.f, B0 = 0.f, A1 = 1.f, B1 = 0.f;
  for (int j=0;j<CHc;j++){
    const size_t idx = base + (size_t)j*1536;
    const unsigned uf = *(const unsigned*)(gi + idx);
    const unsigned ui = *(const unsigned*)(gi + idx + 512);
    const unsigned uh = *(const unsigned*)(gi + idx + 1024);
    float fp, ig;
    gate_lin(bfu(uf & 0xffffu), bfu(ui & 0xffffu), bfu(uh & 0xffffu), fp, ig);
    A0 *= fp; B0 = fp*B0 + ig;
    gate_lin(bfu(uf >> 16), bfu(ui >> 16), bfu(uh >> 16), fp, ig);
    A1 *= fp; B1 = fp*B1 + ig;
  }
  const int o = ((b*NCc + c) << 8) + hp;               // float2 index
  ((float2*)Aagg)[o] = make_float2(A0, A1);
  ((float2*)Bagg)[o] = make_float2(B0, B1);
}

__global__ __launch_bounds__(256)
void scan_phaseB(const float* __restrict__ h0, const float* __restrict__ Aagg,
                 const float* __restrict__ Bagg, float* __restrict__ Vst,
                 float* __restrict__ hlast)
{
  const int gid = blockIdx.x*256 + threadIdx.x;        // b*512 + h
  const int h = gid & 511, b = gid >> 9;
  float v = g_of(h0[gid]);
  for (int c=0;c<NCc;c++){
    const int idx = (b*NCc + c)*Hn + h;
    Vst[idx] = v;
    v = fmaf(Aagg[idx], v, Bagg[idx]);
  }
  hlast[gid] = v;
}

__global__ __launch_bounds__(256)
void scan_phaseC(const __hip_bfloat16* __restrict__ gi, const float* __restrict__ Vst,
                 __hip_bfloat16* __restrict__ hseq)
{
  const int gid = blockIdx.x*256 + threadIdx.x;        // (b, c, hp)
  const int hp = gid & 255, c = (gid >> 8) & 127, b = gid >> 15;
  size_t gbase = ((size_t)b*Sn + (size_t)c*CHc)*1536 + 2*hp;
  size_t obase = ((size_t)b*Sn + (size_t)c*CHc)*Hn  + 2*hp;
  const float2 v2 = ((const float2*)Vst)[((b*NCc + c) << 8) + hp];
  float v0 = v2.x, v1 = v2.y;
  for (int j=0;j<CHc;j++){
    const size_t idx = gbase + (size_t)j*1536;
    const unsigned uf = *(const unsigned*)(gi + idx);
    const unsigned ui = *(const unsigned*)(gi + idx + 512);
    const unsigned uh = *(const unsigned*)(gi + idx + 1024);
    float fp, ig;
    gate_lin(bfu(uf & 0xffffu), bfu(ui & 0xffffu), bfu(uh & 0xffffu), fp, ig);
    v0 = fmaf(fp, v0, ig);
    gate_lin(bfu(uf >> 16), bfu(ui >> 16), bfu(uh >> 16), fp, ig);
    v1 = fmaf(fp, v1, ig);
    __hip_bfloat162 o; o.x = __float2bfloat16(v0); o.y = __float2bfloat16(v1);
    *(__hip_bfloat162*)(hseq + obase + (size_t)j*Hn) = o;
  }
}

// ---------- merged weight prep: one launch for all conversions ----------
// segments: wg3(786432) | wout(262144) | wm1(1048576) | wm2(1048576) |
//           wcv(1048576) | bg3(1536)
__global__ void prep_all(const float* __restrict__ lf_w, const float* __restrict__ li_w,
                         const float* __restrict__ lh_w, const float* __restrict__ out_w,
                         const float* __restrict__ w1, const float* __restrict__ w2,
                         const float* __restrict__ conv_w,
                         const float* __restrict__ lf_b, const float* __restrict__ li_b,
                         const float* __restrict__ lh_b,
                         __hip_bfloat16* __restrict__ wg3, __hip_bfloat16* __restrict__ wout,
                         __hip_bfloat16* __restrict__ wm1, __hip_bfloat16* __restrict__ wm2,
                         __hip_bfloat16* __restrict__ wcv, float* __restrict__ bg3)
{
  int i = blockIdx.x*256 + threadIdx.x;
  if (i < 786432){
    const float* src = (i < 262144) ? lf_w : ((i < 524288) ? li_w : lh_w);
    wg3[i] = __float2bfloat16(src[i & 262143]);
    return;
  }
  i -= 786432;
  if (i < 262144){ wout[i] = __float2bfloat16(out_w[i]); return; }
  i -= 262144;
  if (i < 1048576){ wm1[i] = __float2bfloat16(w1[i]); return; }
  i -= 1048576;
  if (i < 1048576){ wm2[i] = __float2bfloat16(w2[i]); return; }
  i -= 1048576;
  if (i < 1048576){
    const int o = i >> 11, r = i & 2047, tap = r >> 9, ii = r & 511;
    wcv[i] = __float2bfloat16(conv_w[(o*512 + ii)*4 + tap]);
    return;
  }
  i -= 1048576;
  if (i < 1536) bg3[i] = (i < 512) ? lf_b[i] : ((i < 1024) ? li_b[i-512] : lh_b[i-1024]);
}

__global__ void pad_zero(__hip_bfloat16* __restrict__ padded){
  const int gid = blockIdx.x*256 + threadIdx.x;        // 8*3*512
  if (gid < Bn*3*En){
    const int b = gid / (3*En);
    const int j = gid % (3*En);
    const int which = j >> 9, e = j & 511;
    const int u = (which == 0) ? 0 : (4096 + which);   // rows 0, 4097, 4098
    padded[((size_t)b*(Sn+3) + u)*En + e] = __float2bfloat16(0.f);
  }
}

extern "C" void kernel_launch(void* const* d_in, const int* in_sizes, int n_in,
                              void* d_out, int out_size, void* d_ws, size_t ws_size,
                              hipStream_t stream)
{
  const float* x     = (const float*)d_in[0];
  const float* h0    = (const float*)d_in[1];
  const float* lf_w  = (const float*)d_in[2];
  const float* lf_b  = (const float*)d_in[3];
  const float* li_w  = (const float*)d_in[4];
  const float* li_b  = (const float*)d_in[5];
  const float* lh_w  = (const float*)d_in[6];
  const float* lh_b  = (const float*)d_in[7];
  const float* out_w = (const float*)d_in[8];
  const float* out_b = (const float*)d_in[9];
  const float* conv_w= (const float*)d_in[10];
  const float* conv_b= (const float*)d_in[11];
  const float* ln_g  = (const float*)d_in[12];
  const float* ln_b  = (const float*)d_in[13];
  const float* w1    = (const float*)d_in[14];
  const float* b1    = (const float*)d_in[15];
  const float* w2    = (const float*)d_in[16];
  const float* b2    = (const float*)d_in[17];

  float* outx = (float*)d_out;
  float* outh = outx + (size_t)Mn*En;

  // ---- workspace layout (overlay plan) ----
  const size_t AGG = (size_t)Bn*NCc*Hn*4;              // 2 MB each
  const size_t NEED = 5*SLOT + 3*AGG + 8388608 + 6144;
  if (ws_size < NEED) return;

  char* W = (char*)d_ws;
  __hip_bfloat16* GI   = (__hip_bfloat16*)(W);
  __hip_bfloat16* X2   = (__hip_bfloat16*)(W);
  __hip_bfloat16* G1   = (__hip_bfloat16*)(W + SLOT);
  __hip_bfloat16* X3   = (__hip_bfloat16*)(W + 2*SLOT);
  __hip_bfloat16* HSEQ = (__hip_bfloat16*)(W + 3*SLOT);
  __hip_bfloat16* hmid = (__hip_bfloat16*)(W);
  __hip_bfloat16* XN1  = (__hip_bfloat16*)(W + 4*SLOT);   // later XN3
  float* Aagg = (float*)(W + 5*SLOT);
  float* Bagg = Aagg + (size_t)Bn*NCc*Hn;
  float* Vst  = Bagg + (size_t)Bn*NCc*Hn;
  __hip_bfloat16* wg3  = (__hip_bfloat16*)(Vst + (size_t)Bn*NCc*Hn);
  __hip_bfloat16* wout = wg3  + 1536*512;
  __hip_bfloat16* wcv  = wout + 512*512;
  __hip_bfloat16* wm1  = wcv  + 512*2048;
  __hip_bfloat16* wm2  = wm1  + 2048*512;
  float* bg3 = (float*)(wm2 + 512*2048);

  // merged weight prep: 4,195,840 elements in ONE launch (was 8 launches)
  prep_all<<<16391, 256, 0, stream>>>(lf_w, li_w, lh_w, out_w, w1, w2, conv_w,
                                      lf_b, li_b, lh_b,
                                      wg3, wout, wm1, wm2, wcv, bg3);

  // LN1: x(f32) -> XN1 bf16
  ln_k<true><<<Mn, 256, 0, stream>>>(x, ln_g, ln_b, XN1, 0, 0);

  // fused gate GEMM: [Mn,512] x [1536,512]^T -> GI [Mn,1536]   (128 x 12 tiles)
  gemm_bf16<0,false,false><<<1536, 512, 0, stream>>>(XN1, wg3, 1536, 512, 512, 0, bg3, nullptr, 0,0,0, GI);

  // linear-space chunked scan -> HSEQ bf16, h_last f32
  scan_phaseA<<<1024, 256, 0, stream>>>(GI, Aagg, Bagg);
  scan_phaseB<<<16,   256, 0, stream>>>(h0, Aagg, Bagg, Vst, outh);
  scan_phaseC<<<1024, 256, 0, stream>>>(GI, Vst, HSEQ);

  // zero pad rows of G1 (after GI is dead — G1 overlays S1)
  pad_zero<<<48, 256, 0, stream>>>(G1);

  // out-proj + residual(XN1) -> X2 bf16   (128 x 4 tiles)
  gemm_bf16<1,false,false><<<512, 512, 0, stream>>>(HSEQ, wout, 512, 512, 512, 0, out_b, XN1, 512, 0, 0, X2);

  // LN2: X2 -> padded G1 (row t -> padded row t+1)
  ln_k<false><<<Mn, 256, 0, stream>>>(X2, ln_g, ln_b, G1, 3*En, En);

  // conv as K=2048 GEMM over padded rows + residual(xn2 from G1) -> X3 bf16
  gemm_bf16<1,false,false><<<512, 512, 0, stream>>>(G1, wcv, 512, 2048, 512, 3*En, conv_b, G1, 512, 3*En, En, X3);

  // LN3: X3 -> XN3 bf16 (reuses XN1 slot)
  ln_k<false><<<Mn, 256, 0, stream>>>(X3, ln_g, ln_b, XN1, 0, 0);

  // MLP: relu(XN3 @ w1^T) -> hmid (128 x 16 tiles);  hmid @ w2^T + XN3 -> outx (f32)
  gemm_bf16<0,true ,false><<<2048, 512, 0, stream>>>(XN1, wm1, 2048, 512, 512, 0, b1, nullptr, 0,0,0, hmid);
  gemm_bf16<1,false,true ><<<512,  512, 0, stream>>>(hmid, wm2, 512, 2048, 2048, 0, b2, XN1, 512, 0, 0, outx);
}

// Round 21
// 464.998 us; speedup vs baseline: 1.0883x; 1.0883x over previous
//
#include <hip/hip_runtime.h>
#include <hip/hip_bf16.h>

typedef __attribute__((ext_vector_type(8))) short bf16x8v;
typedef __attribute__((ext_vector_type(4))) float f32x4v;

#define DEV __device__ __forceinline__

constexpr int Bn = 8, Sn = 4096, En = 512, Hn = 512;
constexpr int Mn = Bn * Sn;          // 32768 rows
constexpr int NCc = 128, CHc = 32;   // scan: 128 chunks of 32
constexpr size_t SLOT = 33579008;    // = 8*4099*512*2 bytes (padded-conv buffer), 4096-aligned

// ---------- math helpers ----------
DEV float bfu(unsigned u){ union{unsigned v; float f;} c; c.v = u << 16; return c.f; }

DEV void gload16(const void* g, void* l){
  __builtin_amdgcn_global_load_lds((const __attribute__((address_space(1))) void*)g,
                                   (__attribute__((address_space(3))) void*)l, 16, 0, 0);
}

// linear-space gates: f' = (1+e^-i)/(2+e^-f+e^-i), i' = (1+e^-f)/(...), g = x>=0? x+.5 : sigmoid(x)
DEV void gate_lin(float f, float i, float hp, float& fp, float& ig){
  const float ef = __expf(-f);
  const float ei = __expf(-i);
  const float rd = 1.f / (2.f + ef + ei);
  fp = (1.f + ei) * rd;
  const float ipv = (1.f + ef) * rd;
  const float g = (hp >= 0.f) ? (hp + 0.5f) : (1.f / (1.f + __expf(-hp)));
  ig = ipv * g;
}

DEV float g_of(float x){ return (x >= 0.f) ? (x + 0.5f) : (1.f / (1.f + __expf(-x))); }

// ---------- bf16 MFMA GEMM, 256x128 tile, BK=32, 8 waves (4Mx2N), 512 thr ----------
// BEST-KNOWN (r17): 2 blocks/CU (3-buffer 72KB LDS, (512,4) -> 56 VGPR no
// spill), coalesced staging (4 lanes per 64B row-line) with involutive
// chunk-XOR cs=cp^((row>>1)&3) on both global source and ds_read address,
// ONE barrier per K-tile. Ladder: r4 164us -> r7 117 -> r14 94 -> r17 87us
// per big GEMM (~780-800 TF).
// C[M,N] = A(row-mapped)[M,K] * Bw[N,K]^T + bias
// RES: 0 none, 1 add bf16 residual at res[r*rRS + (r>>12)*rBP + rOff + c]
template<int RES, bool RELU, bool OUTF32>
__global__ __launch_bounds__(512, 4)
void gemm_bf16(const __hip_bfloat16* __restrict__ A,
               const __hip_bfloat16* __restrict__ Bw,
               int N, int K, int aRS, int aBP,
               const float* __restrict__ bias,
               const __hip_bfloat16* __restrict__ res, int rRS, int rBP, int rOff,
               void* __restrict__ out)
{
  __shared__ __align__(16) __hip_bfloat16 Al[3][256][32];   // 48 KB
  __shared__ __align__(16) __hip_bfloat16 Bl[3][128][32];   // 24 KB
  const int tid  = threadIdx.x;
  const int lane = tid & 63;
  const int w    = tid >> 6;            // 0..7
  const int ntn  = N >> 7;
  // T1: XCD-aware bijective swizzle (all grids are multiples of 8)
  const int nwg = gridDim.x;
  int wg = blockIdx.x;
  if ((nwg & 7) == 0) wg = ((wg & 7) * (nwg >> 3)) + (wg >> 3);
  const int bm = wg / ntn, bn = wg % ntn;
  const int rowBase = bm << 8, colBase = bn << 7;
  const int wm = w >> 1, wn = w & 1;    // 4 x 2 wave grid; wave tile 64x64
  const int r0 = lane & 15, kc = lane >> 4;
  const int rc = (kc ^ ((r0 >> 1) & 3)) << 3;   // XOR'd chunk offset within [32k] row

  f32x4v acc[4][4];
  #pragma unroll
  for (int i=0;i<4;i++)
    #pragma unroll
    for (int j=0;j<4;j++)
      #pragma unroll
      for (int q=0;q<4;q++) acc[i][j][q] = 0.f;

  // coalesced staging slots: slot s -> row=s>>2, cp=s&3; src chunk cs=cp^((row>>1)&3)
  const int ar0 = tid >> 2, acp = tid & 3;
  const int ar1 = 128 + ar0;
  const int acs0 = acp ^ ((ar0 >> 1) & 3);
  const int acs1 = acp ^ ((ar1 >> 1) & 3);
  const int rg0 = rowBase + ar0, rg1 = rowBase + ar1;
  const size_t aoff0 = (size_t)rg0*aRS + (size_t)(rg0>>12)*aBP + (acs0<<3);
  const size_t aoff1 = (size_t)rg1*aRS + (size_t)(rg1>>12)*aBP + (acs1<<3);
  const size_t boff  = (size_t)(colBase + ar0)*K + (acs0<<3);

  auto stageA = [&](int buf, int t){
    const int ke = t << 5;
    gload16(A + aoff0 + ke, &Al[buf][ar0][acp<<3]);
    gload16(A + aoff1 + ke, &Al[buf][ar1][acp<<3]);
  };
  auto stageB = [&](int buf, int t){
    gload16(Bw + boff + (t<<5), &Bl[buf][ar0][acp<<3]);
  };

  const int NT = K >> 5;                // 16 (K=512) or 64 (K=2048)

  // prologue: stage tiles 0 and 1; tile 0 must land (tile 1's 3 stay in flight)
  stageA(0,0); stageB(0,0); stageA(1,1); stageB(1,1);
  asm volatile("s_waitcnt vmcnt(3)" ::: "memory");
  __builtin_amdgcn_s_barrier();

  int cur = 0;
  for (int t=0; t<NT; t++){
    int nb = cur + 2; if (nb >= 3) nb -= 3;
    const bool pre = (t+2 < NT);
    bf16x8v bfv[4], af[2];
    // ---- p0: frags + stageA, then 8 MFMA (no barrier) ----
    #pragma unroll
    for (int ni=0;ni<4;ni++) bfv[ni] = *(const bf16x8v*)&Bl[cur][(wn<<6)+(ni<<4)+r0][rc];
    af[0] = *(const bf16x8v*)&Al[cur][(wm<<6)+r0][rc];
    af[1] = *(const bf16x8v*)&Al[cur][(wm<<6)+16+r0][rc];
    if (pre) stageA(nb, t+2);
    __builtin_amdgcn_s_setprio(1);
    #pragma unroll
    for (int m=0;m<2;m++)
      #pragma unroll
      for (int ni=0;ni<4;ni++)
        acc[m][ni] = __builtin_amdgcn_mfma_f32_16x16x32_bf16(af[m], bfv[ni], acc[m][ni], 0, 0, 0);
    __builtin_amdgcn_s_setprio(0);
    // ---- p1: frags + stageB, single combined wait + barrier, 8 MFMA ----
    af[0] = *(const bf16x8v*)&Al[cur][(wm<<6)+32+r0][rc];
    af[1] = *(const bf16x8v*)&Al[cur][(wm<<6)+48+r0][rc];
    if (pre) stageB(nb, t+2);
    if (pre) asm volatile("s_waitcnt vmcnt(3) lgkmcnt(0)" ::: "memory");
    else     asm volatile("s_waitcnt vmcnt(0) lgkmcnt(0)" ::: "memory");
    __builtin_amdgcn_s_barrier();
    __builtin_amdgcn_s_setprio(1);
    #pragma unroll
    for (int m=0;m<2;m++)
      #pragma unroll
      for (int ni=0;ni<4;ni++)
        acc[2+m][ni] = __builtin_amdgcn_mfma_f32_16x16x32_bf16(af[m], bfv[ni], acc[2+m][ni], 0, 0, 0);
    __builtin_amdgcn_s_setprio(0);
    cur = (cur + 1 == 3) ? 0 : cur + 1;
  }

  float* outF = (float*)out;
  __hip_bfloat16* outH = (__hip_bfloat16*)out;
  const int q = lane >> 4;
  float bia[4];
  #pragma unroll
  for (int ni=0;ni<4;ni++) bia[ni] = bias[colBase + (wn<<6) + (ni<<4) + r0];
  #pragma unroll
  for (int mi=0;mi<4;mi++){
    const int rb = rowBase + (wm<<6) + (mi<<4) + (q<<2);
    #pragma unroll
    for (int j=0;j<4;j++){
      const int r = rb + j;
      #pragma unroll
      for (int ni=0;ni<4;ni++){        // ni innermost: adjacent 32B chunks per row
        const int c = colBase + (wn<<6) + (ni<<4) + r0;
        float v = acc[mi][ni][j] + bia[ni];
        if constexpr (RES==1) v += __bfloat162float(res[(size_t)r*rRS + (size_t)(r>>12)*rBP + rOff + c]);
        if constexpr (RELU)   v = fmaxf(v, 0.f);
        if constexpr (OUTF32) outF[(size_t)r*N + c] = v;
        else                  outH[(size_t)r*N + c] = __float2bfloat16(v);
      }
    }
  }
}

// ---------- LayerNorm, WAVE-per-row (no LDS, no __syncthreads) ----------
// block = 4 rows (4 waves); lane owns 8 contiguous elems; butterfly shfl_xor
template<bool INF32>
__global__ __launch_bounds__(256)
void ln_k(const void* __restrict__ xin, const float* __restrict__ g, const float* __restrict__ bta,
          __hip_bfloat16* __restrict__ outB, int bBP, int bOff)
{
  const int lane = threadIdx.x & 63, wv = threadIdx.x >> 6;
  const int row  = (blockIdx.x << 2) + wv;
  float v[8];
  if constexpr (INF32){
    const float4* p = (const float4*)((const float*)xin + (size_t)row*En);
    const float4 a = p[lane*2], b = p[lane*2+1];
    v[0]=a.x; v[1]=a.y; v[2]=a.z; v[3]=a.w; v[4]=b.x; v[5]=b.y; v[6]=b.z; v[7]=b.w;
  } else {
    const bf16x8v u = *(const bf16x8v*)((const __hip_bfloat16*)xin + (size_t)row*En + (lane<<3));
    #pragma unroll
    for (int j=0;j<8;j++) v[j] = bfu((unsigned)(unsigned short)u[j]);
  }
  float s = 0.f, sq = 0.f;
  #pragma unroll
  for (int j=0;j<8;j++){ s += v[j]; sq += v[j]*v[j]; }
  #pragma unroll
  for (int off=32; off; off>>=1){ s += __shfl_xor(s, off); sq += __shfl_xor(sq, off); }
  const float mu   = s * (1.f/En);
  const float rstd = rsqrtf(sq * (1.f/En) - mu*mu + 1e-5f);
  const float4 g0 = ((const float4*)g)[lane*2],   g1 = ((const float4*)g)[lane*2+1];
  const float4 b0 = ((const float4*)bta)[lane*2], b1 = ((const float4*)bta)[lane*2+1];
  const float gv[8] = {g0.x,g0.y,g0.z,g0.w,g1.x,g1.y,g1.z,g1.w};
  const float bv[8] = {b0.x,b0.y,b0.z,b0.w,b1.x,b1.y,b1.z,b1.w};
  union { bf16x8v v8; __hip_bfloat16 h[8]; } ou;
  #pragma unroll
  for (int j=0;j<8;j++) ou.h[j] = __float2bfloat16((v[j]-mu)*rstd*gv[j] + bv[j]);
  const size_t base = (size_t)row*En + (size_t)(row>>12)*bBP + bOff + (lane<<3);
  *(bf16x8v*)(outB + base) = ou.v8;
}

// ---------- linear-space chunked scan over gates packed [row][1536] = f | i | h~ ----------
// 4 h-values per thread: 8B uint2 loads per gate, float4 aggregate stores
__global__ __launch_bounds__(256)
void scan_phaseA(const __hip_bfloat16* __restrict__ gi,
                 float* __restrict__ Aagg, float* __restrict__ Bagg)
{
  const int gid = blockIdx.x*256 + threadIdx.x;        // 131072 = (b, c, hq)
  const int hq = gid & 127, c = (gid >> 7) & 127, b = gid >> 14;
  size_t base = ((size_t)b*Sn + (size_t)c*CHc)*1536 + (hq<<2);
  float Aa[4] = {1.f,1.f,1.f,1.f}, Bb[4] = {0.f,0.f,0.f,0.f};
  for (int j=0;j<CHc;j++){
    const size_t idx = base + (size_t)j*1536;
    const uint2 uf = *(const uint2*)(gi + idx);
    const uint2 ui = *(const uint2*)(gi + idx + 512);
    const uint2 uh = *(const uint2*)(gi + idx + 1024);
    const float f[4] = {bfu(uf.x & 0xffffu), bfu(uf.x >> 16), bfu(uf.y & 0xffffu), bfu(uf.y >> 16)};
    const float i4[4]= {bfu(ui.x & 0xffffu), bfu(ui.x >> 16), bfu(ui.y & 0xffffu), bfu(ui.y >> 16)};
    const float h4[4]= {bfu(uh.x & 0xffffu), bfu(uh.x >> 16), bfu(uh.y & 0xffffu), bfu(uh.y >> 16)};
    #pragma unroll
    for (int k=0;k<4;k++){
      float fp, ig;
      gate_lin(f[k], i4[k], h4[k], fp, ig);
      Aa[k] *= fp; Bb[k] = fp*Bb[k] + ig;
    }
  }
  const int o = ((b*NCc + c) << 7) + hq;               // float4 index
  ((float4*)Aagg)[o] = make_float4(Aa[0],Aa[1],Aa[2],Aa[3]);
  ((float4*)Bagg)[o] = make_float4(Bb[0],Bb[1],Bb[2],Bb[3]);
}

__global__ __launch_bounds__(256)
void scan_phaseB(const float* __restrict__ h0, const float* __restrict__ Aagg,
                 const float* __restrict__ Bagg, float* __restrict__ Vst,
                 float* __restrict__ hlast)
{
  const int gid = blockIdx.x*256 + threadIdx.x;        // b*512 + h
  const int h = gid & 511, b = gid >> 9;
  float v = g_of(h0[gid]);
  for (int c=0;c<NCc;c++){
    const int idx = (b*NCc + c)*Hn + h;
    Vst[idx] = v;
    v = fmaf(Aagg[idx], v, Bagg[idx]);
  }
  hlast[gid] = v;
}

__global__ __launch_bounds__(256)
void scan_phaseC(const __hip_bfloat16* __restrict__ gi, const float* __restrict__ Vst,
                 __hip_bfloat16* __restrict__ hseq)
{
  const int gid = blockIdx.x*256 + threadIdx.x;        // (b, c, hq)
  const int hq = gid & 127, c = (gid >> 7) & 127, b = gid >> 14;
  size_t gbase = ((size_t)b*Sn + (size_t)c*CHc)*1536 + (hq<<2);
  size_t obase = ((size_t)b*Sn + (size_t)c*CHc)*Hn  + (hq<<2);
  const float4 v4 = ((const float4*)Vst)[((b*NCc + c) << 7) + hq];
  float v[4] = {v4.x, v4.y, v4.z, v4.w};
  for (int j=0;j<CHc;j++){
    const size_t idx = gbase + (size_t)j*1536;
    const uint2 uf = *(const uint2*)(gi + idx);
    const uint2 ui = *(const uint2*)(gi + idx + 512);
    const uint2 uh = *(const uint2*)(gi + idx + 1024);
    const float f[4] = {bfu(uf.x & 0xffffu), bfu(uf.x >> 16), bfu(uf.y & 0xffffu), bfu(uf.y >> 16)};
    const float i4[4]= {bfu(ui.x & 0xffffu), bfu(ui.x >> 16), bfu(ui.y & 0xffffu), bfu(ui.y >> 16)};
    const float h4[4]= {bfu(uh.x & 0xffffu), bfu(uh.x >> 16), bfu(uh.y & 0xffffu), bfu(uh.y >> 16)};
    union { uint2 u; __hip_bfloat16 h[4]; } pk;
    #pragma unroll
    for (int k=0;k<4;k++){
      float fp, ig;
      gate_lin(f[k], i4[k], h4[k], fp, ig);
      v[k] = fmaf(fp, v[k], ig);
      pk.h[k] = __float2bfloat16(v[k]);
    }
    *(uint2*)(hseq + obase + (size_t)j*Hn) = pk.u;
  }
}

// ---------- merged weight prep: one launch for all conversions ----------
__global__ void prep_all(const float* __restrict__ lf_w, const float* __restrict__ li_w,
                         const float* __restrict__ lh_w, const float* __restrict__ out_w,
                         const float* __restrict__ w1, const float* __restrict__ w2,
                         const float* __restrict__ conv_w,
                         const float* __restrict__ lf_b, const float* __restrict__ li_b,
                         const float* __restrict__ lh_b,
                         __hip_bfloat16* __restrict__ wg3, __hip_bfloat16* __restrict__ wout,
                         __hip_bfloat16* __restrict__ wm1, __hip_bfloat16* __restrict__ wm2,
                         __hip_bfloat16* __restrict__ wcv, float* __restrict__ bg3)
{
  int i = blockIdx.x*256 + threadIdx.x;
  if (i < 786432){
    const float* src = (i < 262144) ? lf_w : ((i < 524288) ? li_w : lh_w);
    wg3[i] = __float2bfloat16(src[i & 262143]);
    return;
  }
  i -= 786432;
  if (i < 262144){ wout[i] = __float2bfloat16(out_w[i]); return; }
  i -= 262144;
  if (i < 1048576){ wm1[i] = __float2bfloat16(w1[i]); return; }
  i -= 1048576;
  if (i < 1048576){ wm2[i] = __float2bfloat16(w2[i]); return; }
  i -= 1048576;
  if (i < 1048576){
    const int o = i >> 11, r = i & 2047, tap = r >> 9, ii = r & 511;
    wcv[i] = __float2bfloat16(conv_w[(o*512 + ii)*4 + tap]);
    return;
  }
  i -= 1048576;
  if (i < 1536) bg3[i] = (i < 512) ? lf_b[i] : ((i < 1024) ? li_b[i-512] : lh_b[i-1024]);
}

__global__ void pad_zero(__hip_bfloat16* __restrict__ padded){
  const int gid = blockIdx.x*256 + threadIdx.x;        // 8*3*512
  if (gid < Bn*3*En){
    const int b = gid / (3*En);
    const int j = gid % (3*En);
    const int which = j >> 9, e = j & 511;
    const int u = (which == 0) ? 0 : (4096 + which);   // rows 0, 4097, 4098
    padded[((size_t)b*(Sn+3) + u)*En + e] = __float2bfloat16(0.f);
  }
}

extern "C" void kernel_launch(void* const* d_in, const int* in_sizes, int n_in,
                              void* d_out, int out_size, void* d_ws, size_t ws_size,
                              hipStream_t stream)
{
  const float* x     = (const float*)d_in[0];
  const float* h0    = (const float*)d_in[1];
  const float* lf_w  = (const float*)d_in[2];
  const float* lf_b  = (const float*)d_in[3];
  const float* li_w  = (const float*)d_in[4];
  const float* li_b  = (const float*)d_in[5];
  const float* lh_w  = (const float*)d_in[6];
  const float* lh_b  = (const float*)d_in[7];
  const float* out_w = (const float*)d_in[8];
  const float* out_b = (const float*)d_in[9];
  const float* conv_w= (const float*)d_in[10];
  const float* conv_b= (const float*)d_in[11];
  const float* ln_g  = (const float*)d_in[12];
  const float* ln_b  = (const float*)d_in[13];
  const float* w1    = (const float*)d_in[14];
  const float* b1    = (const float*)d_in[15];
  const float* w2    = (const float*)d_in[16];
  const float* b2    = (const float*)d_in[17];

  float* outx = (float*)d_out;
  float* outh = outx + (size_t)Mn*En;

  // ---- workspace layout (overlay plan) ----
  const size_t AGG = (size_t)Bn*NCc*Hn*4;              // 2 MB each
  const size_t NEED = 5*SLOT + 3*AGG + 8388608 + 6144;
  if (ws_size < NEED) return;

  char* W = (char*)d_ws;
  __hip_bfloat16* GI   = (__hip_bfloat16*)(W);
  __hip_bfloat16* X2   = (__hip_bfloat16*)(W);
  __hip_bfloat16* G1   = (__hip_bfloat16*)(W + SLOT);
  __hip_bfloat16* X3   = (__hip_bfloat16*)(W + 2*SLOT);
  __hip_bfloat16* HSEQ = (__hip_bfloat16*)(W + 3*SLOT);
  __hip_bfloat16* hmid = (__hip_bfloat16*)(W);
  __hip_bfloat16* XN1  = (__hip_bfloat16*)(W + 4*SLOT);   // later XN3
  float* Aagg = (float*)(W + 5*SLOT);
  float* Bagg = Aagg + (size_t)Bn*NCc*Hn;
  float* Vst  = Bagg + (size_t)Bn*NCc*Hn;
  __hip_bfloat16* wg3  = (__hip_bfloat16*)(Vst + (size_t)Bn*NCc*Hn);
  __hip_bfloat16* wout = wg3  + 1536*512;
  __hip_bfloat16* wcv  = wout + 512*512;
  __hip_bfloat16* wm1  = wcv  + 512*2048;
  __hip_bfloat16* wm2  = wm1  + 2048*512;
  float* bg3 = (float*)(wm2 + 512*2048);

  // merged weight prep: one launch
  prep_all<<<16391, 256, 0, stream>>>(lf_w, li_w, lh_w, out_w, w1, w2, conv_w,
                                      lf_b, li_b, lh_b,
                                      wg3, wout, wm1, wm2, wcv, bg3);

  // LN1: x(f32) -> XN1 bf16   (wave-per-row, 4 rows/block)
  ln_k<true><<<Mn/4, 256, 0, stream>>>(x, ln_g, ln_b, XN1, 0, 0);

  // fused gate GEMM: [Mn,512] x [1536,512]^T -> GI [Mn,1536]
  gemm_bf16<0,false,false><<<1536, 512, 0, stream>>>(XN1, wg3, 1536, 512, 512, 0, bg3, nullptr, 0,0,0, GI);

  // linear-space chunked scan -> HSEQ bf16, h_last f32
  scan_phaseA<<<512, 256, 0, stream>>>(GI, Aagg, Bagg);
  scan_phaseB<<<16,  256, 0, stream>>>(h0, Aagg, Bagg, Vst, outh);
  scan_phaseC<<<512, 256, 0, stream>>>(GI, Vst, HSEQ);

  // zero pad rows of G1 (after GI is dead — G1 overlays S1)
  pad_zero<<<48, 256, 0, stream>>>(G1);

  // out-proj + residual(XN1) -> X2 bf16
  gemm_bf16<1,false,false><<<512, 512, 0, stream>>>(HSEQ, wout, 512, 512, 512, 0, out_b, XN1, 512, 0, 0, X2);

  // LN2: X2 -> padded G1 (row t -> padded row t+1)
  ln_k<false><<<Mn/4, 256, 0, stream>>>(X2, ln_g, ln_b, G1, 3*En, En);

  // conv as K=2048 GEMM over padded rows + residual(xn2 from G1) -> X3 bf16
  gemm_bf16<1,false,false><<<512, 512, 0, stream>>>(G1, wcv, 512, 2048, 512, 3*En, conv_b, G1, 512, 3*En, En, X3);

  // LN3: X3 -> XN3 bf16 (reuses XN1 slot)
  ln_k<false><<<Mn/4, 256, 0, stream>>>(X3, ln_g, ln_b, XN1, 0, 0);

  // MLP: relu(XN3 @ w1^T) -> hmid;  hmid @ w2^T + XN3 -> outx (f32)
  gemm_bf16<0,true ,false><<<2048, 512, 0, stream>>>(XN1, wm1, 2048, 512, 512, 0, b1, nullptr, 0,0,0, hmid);
  gemm_bf16<1,false,true ><<<512,  512, 0, stream>>>(hmid, wm2, 512, 2048, 2048, 0, b2, XN1, 512, 0, 0, outx);
}

// Round 23
// 455.903 us; speedup vs baseline: 1.1101x; 1.0200x over previous
//
#include <hip/hip_runtime.h>
#include <hip/hip_bf16.h>

typedef __attribute__((ext_vector_type(8))) short bf16x8v;
typedef __attribute__((ext_vector_type(4))) float f32x4v;

#define DEV __device__ __forceinline__

constexpr int Bn = 8, Sn = 4096, En = 512, Hn = 512;
constexpr int Mn = Bn * Sn;          // 32768 rows
constexpr int NCc = 128, CHc = 32;   // scan: 128 chunks of 32
constexpr size_t SLOT = 33579008;    // = 8*4099*512*2 bytes (padded-conv buffer), 4096-aligned

// ---------- math helpers ----------
DEV float bfu(unsigned u){ union{unsigned v; float f;} c; c.v = u << 16; return c.f; }

DEV void gload16(const void* g, void* l){
  __builtin_amdgcn_global_load_lds((const __attribute__((address_space(1))) void*)g,
                                   (__attribute__((address_space(3))) void*)l, 16, 0, 0);
}

// linear-space gates: f' = (1+e^-i)/(2+e^-f+e^-i), i' = (1+e^-f)/(...), g = x>=0? x+.5 : sigmoid(x)
DEV void gate_lin(float f, float i, float hp, float& fp, float& ig){
  const float ef = __expf(-f);
  const float ei = __expf(-i);
  const float rd = 1.f / (2.f + ef + ei);
  fp = (1.f + ei) * rd;
  const float ipv = (1.f + ef) * rd;
  const float g = (hp >= 0.f) ? (hp + 0.5f) : (1.f / (1.f + __expf(-hp)));
  ig = ipv * g;
}

DEV float g_of(float x){ return (x >= 0.f) ? (x + 0.5f) : (1.f / (1.f + __expf(-x))); }

// ---------- bf16 MFMA GEMM, 256x128 tile, BK=32, 8 waves (4Mx2N), 512 thr ----------
// BEST-KNOWN (r17): 2 blocks/CU (3-buffer 72KB LDS, (512,4) -> 56 VGPR no
// spill), coalesced staging (4 lanes per 64B row-line) with involutive
// chunk-XOR cs=cp^((row>>1)&3) on both global source and ds_read address,
// ONE barrier per K-tile. Ladder: r4 164us -> r7 117 -> r14 94 -> r17 87us
// per big GEMM (~780-800 TF).
// C[M,N] = A(row-mapped)[M,K] * Bw[N,K]^T + bias
// RES: 0 none, 1 add bf16 residual at res[r*rRS + (r>>12)*rBP + rOff + c]
template<int RES, bool RELU, bool OUTF32>
__global__ __launch_bounds__(512, 4)
void gemm_bf16(const __hip_bfloat16* __restrict__ A,
               const __hip_bfloat16* __restrict__ Bw,
               int N, int K, int aRS, int aBP,
               const float* __restrict__ bias,
               const __hip_bfloat16* __restrict__ res, int rRS, int rBP, int rOff,
               void* __restrict__ out)
{
  __shared__ __align__(16) __hip_bfloat16 Al[3][256][32];   // 48 KB
  __shared__ __align__(16) __hip_bfloat16 Bl[3][128][32];   // 24 KB
  const int tid  = threadIdx.x;
  const int lane = tid & 63;
  const int w    = tid >> 6;            // 0..7
  const int ntn  = N >> 7;
  // T1: XCD-aware bijective swizzle (all grids are multiples of 8)
  const int nwg = gridDim.x;
  int wg = blockIdx.x;
  if ((nwg & 7) == 0) wg = ((wg & 7) * (nwg >> 3)) + (wg >> 3);
  const int bm = wg / ntn, bn = wg % ntn;
  const int rowBase = bm << 8, colBase = bn << 7;
  const int wm = w >> 1, wn = w & 1;    // 4 x 2 wave grid; wave tile 64x64
  const int r0 = lane & 15, kc = lane >> 4;
  const int rc = (kc ^ ((r0 >> 1) & 3)) << 3;   // XOR'd chunk offset within [32k] row

  f32x4v acc[4][4];
  #pragma unroll
  for (int i=0;i<4;i++)
    #pragma unroll
    for (int j=0;j<4;j++)
      #pragma unroll
      for (int q=0;q<4;q++) acc[i][j][q] = 0.f;

  // coalesced staging slots: slot s -> row=s>>2, cp=s&3; src chunk cs=cp^((row>>1)&3)
  const int ar0 = tid >> 2, acp = tid & 3;
  const int ar1 = 128 + ar0;
  const int acs0 = acp ^ ((ar0 >> 1) & 3);
  const int acs1 = acp ^ ((ar1 >> 1) & 3);
  const int rg0 = rowBase + ar0, rg1 = rowBase + ar1;
  const size_t aoff0 = (size_t)rg0*aRS + (size_t)(rg0>>12)*aBP + (acs0<<3);
  const size_t aoff1 = (size_t)rg1*aRS + (size_t)(rg1>>12)*aBP + (acs1<<3);
  const size_t boff  = (size_t)(colBase + ar0)*K + (acs0<<3);

  auto stageA = [&](int buf, int t){
    const int ke = t << 5;
    gload16(A + aoff0 + ke, &Al[buf][ar0][acp<<3]);
    gload16(A + aoff1 + ke, &Al[buf][ar1][acp<<3]);
  };
  auto stageB = [&](int buf, int t){
    gload16(Bw + boff + (t<<5), &Bl[buf][ar0][acp<<3]);
  };

  const int NT = K >> 5;                // 16 (K=512) or 64 (K=2048)

  // prologue: stage tiles 0 and 1; tile 0 must land (tile 1's 3 stay in flight)
  stageA(0,0); stageB(0,0); stageA(1,1); stageB(1,1);
  asm volatile("s_waitcnt vmcnt(3)" ::: "memory");
  __builtin_amdgcn_s_barrier();

  int cur = 0;
  for (int t=0; t<NT; t++){
    int nb = cur + 2; if (nb >= 3) nb -= 3;
    const bool pre = (t+2 < NT);
    bf16x8v bfv[4], af[2];
    // ---- p0: frags + stageA, then 8 MFMA (no barrier) ----
    #pragma unroll
    for (int ni=0;ni<4;ni++) bfv[ni] = *(const bf16x8v*)&Bl[cur][(wn<<6)+(ni<<4)+r0][rc];
    af[0] = *(const bf16x8v*)&Al[cur][(wm<<6)+r0][rc];
    af[1] = *(const bf16x8v*)&Al[cur][(wm<<6)+16+r0][rc];
    if (pre) stageA(nb, t+2);
    __builtin_amdgcn_s_setprio(1);
    #pragma unroll
    for (int m=0;m<2;m++)
      #pragma unroll
      for (int ni=0;ni<4;ni++)
        acc[m][ni] = __builtin_amdgcn_mfma_f32_16x16x32_bf16(af[m], bfv[ni], acc[m][ni], 0, 0, 0);
    __builtin_amdgcn_s_setprio(0);
    // ---- p1: frags + stageB, single combined wait + barrier, 8 MFMA ----
    af[0] = *(const bf16x8v*)&Al[cur][(wm<<6)+32+r0][rc];
    af[1] = *(const bf16x8v*)&Al[cur][(wm<<6)+48+r0][rc];
    if (pre) stageB(nb, t+2);
    if (pre) asm volatile("s_waitcnt vmcnt(3) lgkmcnt(0)" ::: "memory");
    else     asm volatile("s_waitcnt vmcnt(0) lgkmcnt(0)" ::: "memory");
    __builtin_amdgcn_s_barrier();
    __builtin_amdgcn_s_setprio(1);
    #pragma unroll
    for (int m=0;m<2;m++)
      #pragma unroll
      for (int ni=0;ni<4;ni++)
        acc[2+m][ni] = __builtin_amdgcn_mfma_f32_16x16x32_bf16(af[m], bfv[ni], acc[2+m][ni], 0, 0, 0);
    __builtin_amdgcn_s_setprio(0);
    cur = (cur + 1 == 3) ? 0 : cur + 1;
  }

  float* outF = (float*)out;
  __hip_bfloat16* outH = (__hip_bfloat16*)out;
  const int q = lane >> 4;
  float bia[4];
  #pragma unroll
  for (int ni=0;ni<4;ni++) bia[ni] = bias[colBase + (wn<<6) + (ni<<4) + r0];
  #pragma unroll
  for (int mi=0;mi<4;mi++){
    const int rb = rowBase + (wm<<6) + (mi<<4) + (q<<2);
    #pragma unroll
    for (int j=0;j<4;j++){
      const int r = rb + j;
      #pragma unroll
      for (int ni=0;ni<4;ni++){        // ni innermost: adjacent 32B chunks per row
        const int c = colBase + (wn<<6) + (ni<<4) + r0;
        float v = acc[mi][ni][j] + bia[ni];
        if constexpr (RES==1) v += __bfloat162float(res[(size_t)r*rRS + (size_t)(r>>12)*rBP + rOff + c]);
        if constexpr (RELU)   v = fmaxf(v, 0.f);
        if constexpr (OUTF32) outF[(size_t)r*N + c] = v;
        else                  outH[(size_t)r*N + c] = __float2bfloat16(v);
      }
    }
  }
}

// ---------- LayerNorm, WAVE-per-row; PAD variant zeroes conv pad rows ----------
template<bool INF32, bool PAD>
__global__ __launch_bounds__(256)
void ln_k(const void* __restrict__ xin, const float* __restrict__ g, const float* __restrict__ bta,
          __hip_bfloat16* __restrict__ outB, int bBP, int bOff)
{
  if constexpr (PAD){
    // last 2 blocks: zero the 8*3*512 pad elements (rows 0, 4097, 4098 per batch)
    // outB is the G1 base; padded row u of batch b lives at (b*4099 + u)*512.
    if (blockIdx.x >= (Mn >> 2)){
      const int p = (blockIdx.x - (Mn >> 2))*256 + threadIdx.x;   // 0..511
      #pragma unroll
      for (int j=0;j<3;j++){
        const int cid = p*3 + j;                                   // 0..1535 (x8 elems)
        const int b = cid / 192, rem = cid % 192;
        const int which = rem >> 6, e8 = rem & 63;
        const int u = (which == 0) ? 0 : (4096 + which);
        bf16x8v z = {0,0,0,0,0,0,0,0};
        *(bf16x8v*)(outB + ((size_t)b*(Sn+3) + u)*En + (e8<<3)) = z;
      }
      return;
    }
  }
  const int lane = threadIdx.x & 63, wv = threadIdx.x >> 6;
  const int row  = (blockIdx.x << 2) + wv;
  float v[8];
  if constexpr (INF32){
    const float4* p = (const float4*)((const float*)xin + (size_t)row*En);
    const float4 a = p[lane*2], b = p[lane*2+1];
    v[0]=a.x; v[1]=a.y; v[2]=a.z; v[3]=a.w; v[4]=b.x; v[5]=b.y; v[6]=b.z; v[7]=b.w;
  } else {
    const bf16x8v u = *(const bf16x8v*)((const __hip_bfloat16*)xin + (size_t)row*En + (lane<<3));
    #pragma unroll
    for (int j=0;j<8;j++) v[j] = bfu((unsigned)(unsigned short)u[j]);
  }
  float s = 0.f, sq = 0.f;
  #pragma unroll
  for (int j=0;j<8;j++){ s += v[j]; sq += v[j]*v[j]; }
  #pragma unroll
  for (int off=32; off; off>>=1){ s += __shfl_xor(s, off); sq += __shfl_xor(sq, off); }
  const float mu   = s * (1.f/En);
  const float rstd = rsqrtf(sq * (1.f/En) - mu*mu + 1e-5f);
  const float4 g0 = ((const float4*)g)[lane*2],   g1 = ((const float4*)g)[lane*2+1];
  const float4 b0 = ((const float4*)bta)[lane*2], b1 = ((const float4*)bta)[lane*2+1];
  const float gv[8] = {g0.x,g0.y,g0.z,g0.w,g1.x,g1.y,g1.z,g1.w};
  const float bv[8] = {b0.x,b0.y,b0.z,b0.w,b1.x,b1.y,b1.z,b1.w};
  union { bf16x8v v8; __hip_bfloat16 h[8]; } ou;
  #pragma unroll
  for (int j=0;j<8;j++) ou.h[j] = __float2bfloat16((v[j]-mu)*rstd*gv[j] + bv[j]);
  const size_t base = (size_t)row*En + (size_t)(row>>12)*bBP + bOff + (lane<<3);
  *(bf16x8v*)(outB + base) = ou.v8;
}

// ---------- linear-space chunked scan over gates packed [row][1536] = f | i | h~ ----------
__global__ __launch_bounds__(256)
void scan_phaseA(const __hip_bfloat16* __restrict__ gi,
                 float* __restrict__ Aagg, float* __restrict__ Bagg)
{
  const int gid = blockIdx.x*256 + threadIdx.x;        // 131072 = (b, c, hq)
  const int hq = gid & 127, c = (gid >> 7) & 127, b = gid >> 14;
  size_t base = ((size_t)b*Sn + (size_t)c*CHc)*1536 + (hq<<2);
  float Aa[4] = {1.f,1.f,1.f,1.f}, Bb[4] = {0.f,0.f,0.f,0.f};
  for (int j=0;j<CHc;j++){
    const size_t idx = base + (size_t)j*1536;
    const uint2 uf = *(const uint2*)(gi + idx);
    const uint2 ui = *(const uint2*)(gi + idx + 512);
    const uint2 uh = *(const uint2*)(gi + idx + 1024);
    const float f[4] = {bfu(uf.x & 0xffffu), bfu(uf.x >> 16), bfu(uf.y & 0xffffu), bfu(uf.y >> 16)};
    const float i4[4]= {bfu(ui.x & 0xffffu), bfu(ui.x >> 16), bfu(ui.y & 0xffffu), bfu(ui.y >> 16)};
    const float h4[4]= {bfu(uh.x & 0xffffu), bfu(uh.x >> 16), bfu(uh.y & 0xffffu), bfu(uh.y >> 16)};
    #pragma unroll
    for (int k=0;k<4;k++){
      float fp, ig;
      gate_lin(f[k], i4[k], h4[k], fp, ig);
      Aa[k] *= fp; Bb[k] = fp*Bb[k] + ig;
    }
  }
  const int o = ((b*NCc + c) << 7) + hq;               // float4 index
  ((float4*)Aagg)[o] = make_float4(Aa[0],Aa[1],Aa[2],Aa[3]);
  ((float4*)Bagg)[o] = make_float4(Bb[0],Bb[1],Bb[2],Bb[3]);
}

// phase B: sequential over 128 chunks; software-pipelined loads
__global__ __launch_bounds__(256)
void scan_phaseB(const float* __restrict__ h0, const float* __restrict__ Aagg,
                 const float* __restrict__ Bagg, float* __restrict__ Vst,
                 float* __restrict__ hlast)
{
  const int gid = blockIdx.x*256 + threadIdx.x;        // b*512 + h
  const int h = gid & 511, b = gid >> 9;
  float v = g_of(h0[gid]);
  int idx = b*NCc*Hn + h;
  float a_cur = Aagg[idx], b_cur = Bagg[idx];
  for (int c=0;c<NCc;c++){
    float a_nxt = 0.f, b_nxt = 0.f;
    if (c+1 < NCc){ a_nxt = Aagg[idx + Hn]; b_nxt = Bagg[idx + Hn]; }
    Vst[idx] = v;
    v = fmaf(a_cur, v, b_cur);
    a_cur = a_nxt; b_cur = b_nxt;
    idx += Hn;
  }
  hlast[gid] = v;
}

__global__ __launch_bounds__(256)
void scan_phaseC(const __hip_bfloat16* __restrict__ gi, const float* __restrict__ Vst,
                 __hip_bfloat16* __restrict__ hseq)
{
  const int gid = blockIdx.x*256 + threadIdx.x;        // (b, c, hq)
  const int hq = gid & 127, c = (gid >> 7) & 127, b = gid >> 14;
  size_t gbase = ((size_t)b*Sn + (size_t)c*CHc)*1536 + (hq<<2);
  size_t obase = ((size_t)b*Sn + (size_t)c*CHc)*Hn  + (hq<<2);
  const float4 v4 = ((const float4*)Vst)[((b*NCc + c) << 7) + hq];
  float v[4] = {v4.x, v4.y, v4.z, v4.w};
  for (int j=0;j<CHc;j++){
    const size_t idx = gbase + (size_t)j*1536;
    const uint2 uf = *(const uint2*)(gi + idx);
    const uint2 ui = *(const uint2*)(gi + idx + 512);
    const uint2 uh = *(const uint2*)(gi + idx + 1024);
    const float f[4] = {bfu(uf.x & 0xffffu), bfu(uf.x >> 16), bfu(uf.y & 0xffffu), bfu(uf.y >> 16)};
    const float i4[4]= {bfu(ui.x & 0xffffu), bfu(ui.x >> 16), bfu(ui.y & 0xffffu), bfu(ui.y >> 16)};
    const float h4[4]= {bfu(uh.x & 0xffffu), bfu(uh.x >> 16), bfu(uh.y & 0xffffu), bfu(uh.y >> 16)};
    union { uint2 u; __hip_bfloat16 h[4]; } pk;
    #pragma unroll
    for (int k=0;k<4;k++){
      float fp, ig;
      gate_lin(f[k], i4[k], h4[k], fp, ig);
      v[k] = fmaf(fp, v[k], ig);
      pk.h[k] = __float2bfloat16(v[k]);
    }
    *(uint2*)(hseq + obase + (size_t)j*Hn) = pk.u;
  }
}

// ---------- merged weight prep: one launch for all conversions ----------
__global__ void prep_all(const float* __restrict__ lf_w, const float* __restrict__ li_w,
                         const float* __restrict__ lh_w, const float* __restrict__ out_w,
                         const float* __restrict__ w1, const float* __restrict__ w2,
                         const float* __restrict__ conv_w,
                         const float* __restrict__ lf_b, const float* __restrict__ li_b,
                         const float* __restrict__ lh_b,
                         __hip_bfloat16* __restrict__ wg3, __hip_bfloat16* __restrict__ wout,
                         __hip_bfloat16* __restrict__ wm1, __hip_bfloat16* __restrict__ wm2,
                         __hip_bfloat16* __restrict__ wcv, float* __restrict__ bg3)
{
  int i = blockIdx.x*256 + threadIdx.x;
  if (i < 786432){
    const float* src = (i < 262144) ? lf_w : ((i < 524288) ? li_w : lh_w);
    wg3[i] = __float2bfloat16(src[i & 262143]);
    return;
  }
  i -= 786432;
  if (i < 262144){ wout[i] = __float2bfloat16(out_w[i]); return; }
  i -= 262144;
  if (i < 1048576){ wm1[i] = __float2bfloat16(w1[i]); return; }
  i -= 1048576;
  if (i < 1048576){ wm2[i] = __float2bfloat16(w2[i]); return; }
  i -= 1048576;
  if (i < 1048576){
    const int o = i >> 11, r = i & 2047, tap = r >> 9, ii = r & 511;
    wcv[i] = __float2bfloat16(conv_w[(o*512 + ii)*4 + tap]);
    return;
  }
  i -= 1048576;
  if (i < 1536) bg3[i] = (i < 512) ? lf_b[i] : ((i < 1024) ? li_b[i-512] : lh_b[i-1024]);
}

extern "C" void kernel_launch(void* const* d_in, const int* in_sizes, int n_in,
                              void* d_out, int out_size, void* d_ws, size_t ws_size,
                              hipStream_t stream)
{
  const float* x     = (const float*)d_in[0];
  const float* h0    = (const float*)d_in[1];
  const float* lf_w  = (const float*)d_in[2];
  const float* lf_b  = (const float*)d_in[3];
  const float* li_w  = (const float*)d_in[4];
  const float* li_b  = (const float*)d_in[5];
  const float* lh_w  = (const float*)d_in[6];
  const float* lh_b  = (const float*)d_in[7];
  const float* out_w = (const float*)d_in[8];
  const float* out_b = (const float*)d_in[9];
  const float* conv_w= (const float*)d_in[10];
  const float* conv_b= (const float*)d_in[11];
  const float* ln_g  = (const float*)d_in[12];
  const float* ln_b  = (const float*)d_in[13];
  const float* w1    = (const float*)d_in[14];
  const float* b1    = (const float*)d_in[15];
  const float* w2    = (const float*)d_in[16];
  const float* b2    = (const float*)d_in[17];

  float* outx = (float*)d_out;
  float* outh = outx + (size_t)Mn*En;

  // ---- workspace layout (overlay plan) ----
  const size_t AGG = (size_t)Bn*NCc*Hn*4;              // 2 MB each
  const size_t NEED = 5*SLOT + 3*AGG + 8388608 + 6144;
  if (ws_size < NEED) return;

  char* W = (char*)d_ws;
  __hip_bfloat16* GI   = (__hip_bfloat16*)(W);
  __hip_bfloat16* X2   = (__hip_bfloat16*)(W);
  __hip_bfloat16* G1   = (__hip_bfloat16*)(W + SLOT);
  __hip_bfloat16* X3   = (__hip_bfloat16*)(W + 2*SLOT);
  __hip_bfloat16* HSEQ = (__hip_bfloat16*)(W + 3*SLOT);
  __hip_bfloat16* hmid = (__hip_bfloat16*)(W);
  __hip_bfloat16* XN1  = (__hip_bfloat16*)(W + 4*SLOT);   // later XN3
  float* Aagg = (float*)(W + 5*SLOT);
  float* Bagg = Aagg + (size_t)Bn*NCc*Hn;
  float* Vst  = Bagg + (size_t)Bn*NCc*Hn;
  __hip_bfloat16* wg3  = (__hip_bfloat16*)(Vst + (size_t)Bn*NCc*Hn);
  __hip_bfloat16* wout = wg3  + 1536*512;
  __hip_bfloat16* wcv  = wout + 512*512;
  __hip_bfloat16* wm1  = wcv  + 512*2048;
  __hip_bfloat16* wm2  = wm1  + 2048*512;
  float* bg3 = (float*)(wm2 + 512*2048);

  // merged weight prep: one launch
  prep_all<<<16391, 256, 0, stream>>>(lf_w, li_w, lh_w, out_w, w1, w2, conv_w,
                                      lf_b, li_b, lh_b,
                                      wg3, wout, wm1, wm2, wcv, bg3);

  // LN1: x(f32) -> XN1 bf16   (wave-per-row, 4 rows/block)
  ln_k<true,false><<<Mn/4, 256, 0, stream>>>(x, ln_g, ln_b, XN1, 0, 0);

  // fused gate GEMM: [Mn,512] x [1536,512]^T -> GI [Mn,1536]
  gemm_bf16<0,false,false><<<1536, 512, 0, stream>>>(XN1, wg3, 1536, 512, 512, 0, bg3, nullptr, 0,0,0, GI);

  // linear-space chunked scan -> HSEQ bf16, h_last f32
  scan_phaseA<<<512, 256, 0, stream>>>(GI, Aagg, Bagg);
  scan_phaseB<<<16,  256, 0, stream>>>(h0, Aagg, Bagg, Vst, outh);
  scan_phaseC<<<512, 256, 0, stream>>>(GI, Vst, HSEQ);

  // out-proj + residual(XN1) -> X2 bf16
  gemm_bf16<1,false,false><<<512, 512, 0, stream>>>(HSEQ, wout, 512, 512, 512, 0, out_b, XN1, 512, 0, 0, X2);

  // LN2: X2 -> padded G1 (row t -> padded row t+1); PAD variant zeroes pad rows
  // (G1 overlays S1, dead after scanC; +2 blocks handle the 12288 pad elems)
  ln_k<false,true><<<Mn/4 + 2, 256, 0, stream>>>(X2, ln_g, ln_b, G1, 3*En, En);

  // conv as K=2048 GEMM over padded rows + residual(xn2 from G1) -> X3 bf16
  gemm_bf16<1,false,false><<<512, 512, 0, stream>>>(G1, wcv, 512, 2048, 512, 3*En, conv_b, G1, 512, 3*En, En, X3);

  // LN3: X3 -> XN3 bf16 (reuses XN1 slot)
  ln_k<false,false><<<Mn/4, 256, 0, stream>>>(X3, ln_g, ln_b, XN1, 0, 0);

  // MLP: relu(XN3 @ w1^T) -> hmid;  hmid @ w2^T + XN3 -> outx (f32)
  gemm_bf16<0,true ,false><<<2048, 512, 0, stream>>>(XN1, wm1, 2048, 512, 512, 0, b1, nullptr, 0,0,0, hmid);
  gemm_bf16<1,false,true ><<<512,  512, 0, stream>>>(hmid, wm2, 512, 2048, 2048, 0, b2, XN1, 512, 0, 0, outx);
}